// Round 1
// baseline (131.025 us; speedup 1.0000x reference)
//
#include <hip/hip_runtime.h>
#include <math.h>

// ---- problem constants ----
#define NRAD 48
#define NANG 72
#define HV   3456            // valid hashes = NRAD*NANG
#define HB   3457            // + invalid bin
#define MAXP 64
#define MAXV 3000
#define BLK  256
#define CHT  64              // tiles per scan chunk

// output layout (floats)
#define OFF_VOX 0
#define OFF_C   (MAXV*MAXP*5)          // 960000
#define OFF_N   (OFF_C + MAXV*3)       // 969000
#define OFF_X   (OFF_N + MAXV)         // 972000

// np.linspace(-pi, pi, 73) computed in f64 (step = delta/div; y = i*step + start;
// endpoint forced to stop), then cast to f32 — matches numpy/jax within the
// dataset's empirically boundary-free tolerance.
__device__ __forceinline__ float angle_edge(int j) {
  const double PI = 3.14159265358979311599796346854;  // f64 nearest to pi
  const double step = (PI - (-PI)) / 72.0;
  if (j == 72) return (float)PI;
  return (float)(-PI + (double)j * step);
}

// bin index per reference semantics: searchsorted(edges, v, 'left') - 1, clipped.
__device__ __forceinline__ int point_bin(float x, float y, float z, const float* eang) {
  // r = sqrt(x*x + y*y) with NO fma contraction, IEEE RN ops only
  float xx = __fmul_rn(x, x);
  float yy = __fmul_rn(y, y);
  float s  = __fadd_rn(xx, yy);
  float r  = __fsqrt_rn(s);
  // theta: f64 atan2 rounded to f32 == correctly-rounded f32 (prob ~1-2^-28)
  float th = (float)atan2((double)y, (double)x);
  bool valid = (z >= -3.0f) && (z < 5.0f) && (r >= 2.0f) && (r < 50.0f)
            && (th >= eang[0]) && (th < eang[72]);
  if (!valid) return HV;
  // radial: edges are integers 2..50; count(e < r) - 1 = ceil(r) - 3
  int ri = (int)ceilf(r) - 3;
  ri = max(0, min(NRAD - 1, ri));
  // angular: largest g with eang[g] < th (g in [-1,71]), then clamp
  int g = (int)floorf((th - eang[0]) * 11.459155902616465f); // ~72/(2pi), guess only
  g = max(0, min(NANG - 1, g));
  while (g >= 0 && !(eang[g] < th)) g--;
  while (g < NANG - 1 && eang[g + 1] < th) g++;
  int ti = max(0, min(NANG - 1, g));
  return ri * NANG + ti;
}

// ---- pass 1: per-tile histogram + bin cache ----
__global__ void k_hist(const float* __restrict__ pts, int N, int tile,
                       int* __restrict__ hist, unsigned short* __restrict__ bins) {
  __shared__ int lh[HB];
  __shared__ float eang[73];
  int t = blockIdx.x;
  for (int i = threadIdx.x; i < HB; i += BLK) lh[i] = 0;
  if (threadIdx.x < 73) eang[threadIdx.x] = angle_edge(threadIdx.x);
  __syncthreads();
  int base = t * tile;
  int end  = min(base + tile, N);
  for (int i = base + (int)threadIdx.x; i < end; i += BLK) {
    size_t p = (size_t)i * 5;
    float x = pts[p], y = pts[p + 1], z = pts[p + 2];
    int b = point_bin(x, y, z, eang);
    bins[i] = (unsigned short)b;
    atomicAdd(&lh[b], 1);
  }
  __syncthreads();
  int* ht = hist + (size_t)t * HB;
  for (int i = threadIdx.x; i < HB; i += BLK) ht[i] = lh[i];
}

// ---- pass 2: exclusive scan of hist across tiles, per bin (chunked 2-level) ----
__global__ void k_scan_a(const int* __restrict__ hist, int NT, int* __restrict__ part) {
  int b = blockIdx.x * BLK + threadIdx.x;
  int c = blockIdx.y;
  if (b >= HB) return;
  int t0 = c * CHT, t1 = min(t0 + CHT, NT);
  int s = 0;
  for (int t = t0; t < t1; ++t) s += hist[(size_t)t * HB + b];
  part[(size_t)c * HB + b] = s;
}

__global__ void k_scan_b(int* __restrict__ part, int NC, int* __restrict__ counts) {
  int b = blockIdx.x * BLK + threadIdx.x;
  if (b >= HB) return;
  int run = 0;
  for (int c = 0; c < NC; ++c) {
    size_t o = (size_t)c * HB + b;
    int v = part[o];
    part[o] = run;
    run += v;
  }
  counts[b] = run;
}

__global__ void k_scan_c(int* __restrict__ hist, int NT, const int* __restrict__ part) {
  int b = blockIdx.x * BLK + threadIdx.x;
  int c = blockIdx.y;
  if (b >= HB) return;
  int t0 = c * CHT, t1 = min(t0 + CHT, NT);
  int run = part[(size_t)c * HB + b];
  for (int t = t0; t < t1; ++t) {
    size_t o = (size_t)t * HB + b;
    int v = hist[o];
    hist[o] = run;
    run += v;
  }
}

// ---- pass 3: slot assignment + coords/num_points/centers ----
__global__ void k_slots(const int* __restrict__ counts, int* __restrict__ soh,
                        float* __restrict__ out) {
  __shared__ int ssum[BLK];
  const int PER = (HV + BLK - 1) / BLK;   // 14
  int tid = threadIdx.x;
  int cnt[PER];
  int tsum = 0;
#pragma unroll
  for (int k = 0; k < PER; ++k) {
    int h = tid * PER + k;
    int c = (h < HV) ? counts[h] : 0;
    cnt[k] = c;
    tsum += (c > 0) ? 1 : 0;
  }
  ssum[tid] = tsum;
  __syncthreads();
  for (int off = 1; off < BLK; off <<= 1) {
    int v = (tid >= off) ? ssum[tid - off] : 0;
    __syncthreads();
    ssum[tid] += v;
    __syncthreads();
  }
  int run = ssum[tid] - tsum;   // exclusive base
#pragma unroll
  for (int k = 0; k < PER; ++k) {
    int h = tid * PER + k;
    if (h < HV) {
      int s = -1;
      if (cnt[k] > 0) {
        if (run < MAXV) s = run;
        run++;
      }
      soh[h] = s;
      if (s >= 0) {
        int ri = h / NANG, ti = h % NANG;
        out[OFF_C + s * 3 + 0] = (float)ri;
        out[OFF_C + s * 3 + 1] = (float)ti;
        out[OFF_C + s * 3 + 2] = 0.0f;
        out[OFF_N + s] = (float)min(cnt[k], MAXP);
        float rc = 2.5f + (float)ri;                       // exact: 0.5*(E[ri]+E[ri+1])
        float e0 = angle_edge(ti), e1 = angle_edge(ti + 1);
        float tc = __fmul_rn(0.5f, __fadd_rn(e0, e1));
        float cv = (float)cos((double)tc);
        float sv = (float)sin((double)tc);
        out[OFF_X + s * 2 + 0] = __fmul_rn(rc, cv);
        out[OFF_X + s * 2 + 1] = __fmul_rn(rc, sv);
      }
    }
  }
}

// ---- pass 4: stable rank assignment + scatter of first 64 points/voxel ----
__global__ void k_scatter(const float* __restrict__ pts, int N, int tile,
                          const int* __restrict__ hist,
                          const unsigned short* __restrict__ bins,
                          const int* __restrict__ soh,
                          float* __restrict__ out) {
  __shared__ int cur[HB];
  int t = blockIdx.x;
  int tid = threadIdx.x;
  for (int i = tid; i < HB; i += BLK) cur[i] = hist[(size_t)t * HB + i];
  __syncthreads();
  int base = t * tile;
  int end  = min(base + tile, N);
  int lane = tid & 63, wv = tid >> 6;
  for (int g = base; g < base + tile; g += BLK) {
    int i = g + tid;
    bool act = (i < end);
    int b = act ? (int)bins[i] : 0x10000;   // sentinel never matches a real bin
    // intra-wave stable rank (rho) and per-bin wave count (kap)
    int rho = 0, kap = 0;
    for (int j = 0; j < 64; ++j) {
      int bj = __shfl(b, j, 64);
      if (bj == b) { kap++; if (j < lane) rho++; }
    }
    int rank = 0x7FFFFFFF;
    // wave-serialized cursor update keeps inter-wave order stable
    for (int w = 0; w < 4; ++w) {
      if (wv == w && act) {
        int bs = cur[b];            // same value for all same-bin lanes (read before write)
        rank = bs + rho;
        if (rho == 0) cur[b] = bs + kap;  // distinct b among rho==0 lanes -> no conflict
      }
      __syncthreads();
    }
    if (act && rank < MAXP && b < HV) {
      int s = soh[b];
      if (s >= 0) {
        size_t dst = (size_t)(s * MAXP + rank) * 5;
        size_t src = (size_t)i * 5;
        out[dst + 0] = pts[src + 0];
        out[dst + 1] = pts[src + 1];
        out[dst + 2] = pts[src + 2];
        out[dst + 3] = pts[src + 3];
        out[dst + 4] = pts[src + 4];
      }
    }
  }
}

extern "C" void kernel_launch(void* const* d_in, const int* in_sizes, int n_in,
                              void* d_out, int out_size, void* d_ws, size_t ws_size,
                              hipStream_t stream) {
  const float* pts = (const float*)d_in[0];
  int N = in_sizes[0] / 5;
  float* out = (float*)d_out;

  auto align = [](size_t x) { return (x + 255) & ~(size_t)255; };
  int tile = 4096, NT = 1, NC = 1;
  for (;;) {
    NT = (N + tile - 1) / tile;
    NC = (NT + CHT - 1) / CHT;
    size_t o_hist = 0;
    size_t o_part = align(o_hist + (size_t)NT * HB * 4);
    size_t o_cnts = align(o_part + (size_t)NC * HB * 4);
    size_t o_soh  = align(o_cnts + (size_t)HB * 4);
    size_t o_bins = align(o_soh + (size_t)HV * 4);
    size_t need   = o_bins + (size_t)N * 2;
    if (need <= ws_size || tile >= (1 << 22)) break;
    tile <<= 1;
  }
  size_t o_hist = 0;
  size_t o_part = align(o_hist + (size_t)NT * HB * 4);
  size_t o_cnts = align(o_part + (size_t)NC * HB * 4);
  size_t o_soh  = align(o_cnts + (size_t)HB * 4);
  size_t o_bins = align(o_soh + (size_t)HV * 4);

  char* w = (char*)d_ws;
  int* hist = (int*)(w + o_hist);
  int* part = (int*)(w + o_part);
  int* cnts = (int*)(w + o_cnts);
  int* soh  = (int*)(w + o_soh);
  unsigned short* bins = (unsigned short*)(w + o_bins);

  hipMemsetAsync(d_out, 0, (size_t)out_size * 4, stream);
  k_hist<<<NT, BLK, 0, stream>>>(pts, N, tile, hist, bins);
  dim3 ga((HB + BLK - 1) / BLK, NC);
  k_scan_a<<<ga, BLK, 0, stream>>>(hist, NT, part);
  k_scan_b<<<(HB + BLK - 1) / BLK, BLK, 0, stream>>>(part, NC, cnts);
  k_slots<<<1, BLK, 0, stream>>>(cnts, soh, out);
  k_scan_c<<<ga, BLK, 0, stream>>>(hist, NT, part);
  k_scatter<<<NT, BLK, 0, stream>>>(pts, N, tile, hist, bins, soh, out);
}

// Round 2
// 96.682 us; speedup vs baseline: 1.3552x; 1.3552x over previous
//
#include <hip/hip_runtime.h>
#include <math.h>

// ---- problem constants ----
#define NRAD 48
#define NANG 72
#define HV   3456            // valid hashes = NRAD*NANG
#define HB   3457            // + invalid bin
#define MAXP 64
#define MAXV 3000
#define BLK  256
#define CHT  64              // tiles per scan chunk
#define TILE 4096
#define SUBT 1024            // per-wave sub-tile in fast scatter (TILE/4)
#define NCH  16              // chunks per sub-tile (SUBT/64)

// output layout (floats)
#define OFF_C   (MAXV*MAXP*5)          // 960000
#define OFF_N   (OFF_C + MAXV*3)       // 969000
#define OFF_X   (OFF_N + MAXV)         // 972000

#define PI_F 3.14159265358979323846f   // rounds to 0x40490FDB

// np.linspace(-pi, pi, 73) in f64 (y = i*step + start, endpoint forced), cast f32.
__device__ __forceinline__ float angle_edge(int j) {
  const double PI = 3.14159265358979311599796346854;
  const double step = (PI - (-PI)) / 72.0;
  if (j == 72) return (float)PI;
  return (float)(-PI + (double)j * step);
}

// ---- pass 1: per-tile histogram + bin cache ----
// Fast path: f32 octant-reduced atan estimate (|err| <~ 1.2e-6) decides the
// angular bin when the point is > GUARD from both bin edges; otherwise fall
// back to the exact (float)atan2(f64) path (bit-identical to round-1/reference).
__global__ void k_hist(const float* __restrict__ pts, int N, int tile,
                       int* __restrict__ hist, unsigned short* __restrict__ bins) {
  __shared__ int lh[HB];
  __shared__ float eang[73];
  int t = blockIdx.x;
  for (int i = threadIdx.x; i < HB; i += BLK) lh[i] = 0;
  if (threadIdx.x < 73) eang[threadIdx.x] = angle_edge(threadIdx.x);
  __syncthreads();
  int base = t * tile;
  int end  = min(base + tile, N);
  for (int i = base + (int)threadIdx.x; i < end; i += BLK) {
    size_t p = (size_t)i * 5;
    float x = pts[p], y = pts[p + 1], z = pts[p + 2];
    // r exactly as reference: mul,mul,add,sqrt in RN, no contraction
    float r = __fsqrt_rn(__fadd_rn(__fmul_rn(x, x), __fmul_rn(y, y)));
    int b = HV;
    if (z >= -3.0f && z < 5.0f && r >= 2.0f && r < 50.0f) {
      int ri = (int)ceilf(r) - 3;               // exact: edges are ints 2..50
      ri = max(0, min(NRAD - 1, ri));
      // --- fast theta estimate ---
      float ax = fabsf(x), ay = fabsf(y);
      float u = fminf(ax, ay), U = fmaxf(ax, ay);
      bool big = u > 0.41421356f * U;           // tan(pi/8); either branch valid at tie
      float num = big ? (U - u) : u;
      float den = big ? (U + u) : U;
      float v = num / den;                      // in [0, 0.41422]
      float s = v * v;
      float a = 0.05882353f;                    // 1/17
      a = a * s - 0.06666667f;                  // -1/15
      a = a * s + 0.07692308f;                  // 1/13
      a = a * s - 0.09090909f;                  // -1/11
      a = a * s + 0.11111111f;                  // 1/9
      a = a * s - 0.14285714f;                  // -1/7
      a = a * s + 0.2f;                         // 1/5
      a = a * s - 0.33333333f;                  // -1/3
      a = a * s + 1.0f;
      float pp = v * a;                         // atan(v)
      float th1 = big ? (0.78539816f - pp) : pp;
      if (ay > ax) th1 = 1.57079633f - th1;
      if (x < 0.0f) th1 = PI_F - th1;
      float that = copysignf(th1, y);
      // candidate bin via guess + fixup on the estimate
      int g = (int)floorf((that + PI_F) * 11.459155902616465f);
      g = max(0, min(NANG - 1, g));
      while (g > 0 && !(eang[g] < that)) g--;
      while (g < NANG - 1 && eang[g + 1] < that) g++;
      float d0 = that - eang[g];
      float d1 = eang[g + 1] - that;
      const float GUARD = 2e-5f;
      if (d0 > GUARD && d1 > GUARD) {
        b = ri * NANG + g;                      // far from edges: estimate decides
      } else {
        // --- exact path (rare): bit-identical to reference semantics ---
        float th = (float)atan2((double)y, (double)x);
        if (th >= eang[0] && th < eang[72]) {
          int gg = g;
          while (gg > 0 && !(eang[gg] < th)) gg--;
          while (gg < NANG - 1 && eang[gg + 1] < th) gg++;
          b = ri * NANG + max(0, min(NANG - 1, gg));
        } else {
          b = HV;
        }
      }
    }
    bins[i] = (unsigned short)b;
    atomicAdd(&lh[b], 1);
  }
  __syncthreads();
  int* ht = hist + (size_t)t * HB;
  for (int i = threadIdx.x; i < HB; i += BLK) ht[i] = lh[i];
}

// ---- pass 2: exclusive scan of hist across tiles, per bin (chunked 2-level) ----
__global__ void k_scan_a(const int* __restrict__ hist, int NT, int* __restrict__ part) {
  int b = blockIdx.x * BLK + threadIdx.x;
  int c = blockIdx.y;
  if (b >= HB) return;
  int t0 = c * CHT, t1 = min(t0 + CHT, NT);
  int s = 0;
  for (int t = t0; t < t1; ++t) s += hist[(size_t)t * HB + b];
  part[(size_t)c * HB + b] = s;
}

__global__ void k_scan_b(int* __restrict__ part, int NC, int* __restrict__ counts) {
  int b = blockIdx.x * BLK + threadIdx.x;
  if (b >= HB) return;
  int run = 0;
  for (int c = 0; c < NC; ++c) {
    size_t o = (size_t)c * HB + b;
    int v = part[o];
    part[o] = run;
    run += v;
  }
  counts[b] = run;
}

__global__ void k_scan_c(int* __restrict__ hist, int NT, const int* __restrict__ part) {
  int b = blockIdx.x * BLK + threadIdx.x;
  int c = blockIdx.y;
  if (b >= HB) return;
  int t0 = c * CHT, t1 = min(t0 + CHT, NT);
  int run = part[(size_t)c * HB + b];
  for (int t = t0; t < t1; ++t) {
    size_t o = (size_t)t * HB + b;
    int v = hist[o];
    hist[o] = run;
    run += v;
  }
}

// ---- pass 3a: slot assignment (single block scan over 3456 bins) ----
__global__ void k_slots(const int* __restrict__ counts, int* __restrict__ soh,
                        int* __restrict__ s2h) {
  __shared__ int ssum[BLK];
  const int PER = (HV + BLK - 1) / BLK;   // 14
  int tid = threadIdx.x;
  for (int i = tid; i < MAXV; i += BLK) s2h[i] = -1;
  int cnt[PER];
  int tsum = 0;
#pragma unroll
  for (int k = 0; k < PER; ++k) {
    int h = tid * PER + k;
    int c = (h < HV) ? counts[h] : 0;
    cnt[k] = c;
    tsum += (c > 0) ? 1 : 0;
  }
  ssum[tid] = tsum;
  __syncthreads();
  for (int off = 1; off < BLK; off <<= 1) {
    int v = (tid >= off) ? ssum[tid - off] : 0;
    __syncthreads();
    ssum[tid] += v;
    __syncthreads();
  }
  int run = ssum[tid] - tsum;   // exclusive base
#pragma unroll
  for (int k = 0; k < PER; ++k) {
    int h = tid * PER + k;
    if (h < HV) {
      int s = -1;
      if (cnt[k] > 0) {
        if (run < MAXV) s = run;
        run++;
      }
      soh[h] = s;
      if (s >= 0) s2h[s] = h;
    }
  }
}

// ---- pass 3b: coords / num_points / centers (parallel over slots) ----
__global__ void k_centers(const int* __restrict__ s2h, const int* __restrict__ counts,
                          float* __restrict__ out) {
  int s = blockIdx.x * BLK + threadIdx.x;
  if (s >= MAXV) return;
  int h = s2h[s];
  if (h < 0) return;
  int ri = h / NANG, ti = h % NANG;
  out[OFF_C + s * 3 + 0] = (float)ri;
  out[OFF_C + s * 3 + 1] = (float)ti;
  out[OFF_C + s * 3 + 2] = 0.0f;
  out[OFF_N + s] = (float)min(counts[h], MAXP);
  float rc = 2.5f + (float)ri;
  float e0 = angle_edge(ti), e1 = angle_edge(ti + 1);
  float tc = __fmul_rn(0.5f, __fadd_rn(e0, e1));
  out[OFF_X + s * 2 + 0] = __fmul_rn(rc, (float)cos((double)tc));
  out[OFF_X + s * 2 + 1] = __fmul_rn(rc, (float)sin((double)tc));
}

// ---- pass 4 (fast, tile==4096): ballot-rank scatter, barrier-free main loop ----
// Each of the 4 waves owns a contiguous 1024-pt sub-tile with a private u16
// cursor array in LDS. Stable rank = scanned-hist(tile) + inter-wave prefix +
// intra-wave cursor + intra-chunk ballot rank -> exact ascending-index order.
__global__ __launch_bounds__(BLK) void k_scatter_fast(
    const float* __restrict__ pts, int N,
    const int* __restrict__ hist, const unsigned short* __restrict__ bins,
    const int* __restrict__ soh, float* __restrict__ out) {
  __shared__ unsigned int whd[4 * HV / 2];          // 4 x HV u16 = 27648 B
  unsigned short (*wh)[HV] = (unsigned short (*)[HV])whd;
  int t = blockIdx.x;
  int tid = threadIdx.x;
  int lane = tid & 63, wv = tid >> 6;
  for (int i = tid; i < 4 * HV / 2; i += BLK) whd[i] = 0u;
  __syncthreads();
  int base = t * TILE;
  int end  = min(base + TILE, N);
  int sb = base + wv * SUBT;
  int se = min(sb + SUBT, end);
  unsigned short lb[NCH], lr[NCH];
  const unsigned long long lmask = (1ULL << lane) - 1ULL;
#pragma unroll
  for (int c = 0; c < NCH; ++c) {
    int i = sb + c * 64 + lane;
    int b = 4095;                                   // sentinel (> any real bin)
    if (i < se) { int bi = bins[i]; if (bi < HV) b = bi; }
    unsigned long long m = ~0ULL;
#pragma unroll
    for (int k = 0; k < 12; ++k) {
      unsigned long long bal = __ballot((b >> k) & 1);
      m &= ((b >> k) & 1) ? bal : ~bal;
    }
    int rho = __popcll(m & lmask);                  // same-bin lanes before me
    int kap = __popcll(m);                          // same-bin lanes in chunk
    int cv = 0;
    if (b != 4095) {
      cv = wh[wv][b];                               // read before leader write
      if (rho == 0) wh[wv][b] = (unsigned short)(cv + kap);
    }
    lb[c] = (unsigned short)b;
    lr[c] = (unsigned short)(cv + rho);
  }
  __syncthreads();
  // column prefix across waves: wh[w][j] <- sum_{w'<w} counts
  for (int j = tid; j < HV; j += BLK) {
    int a0 = wh[0][j], a1 = wh[1][j], a2 = wh[2][j];
    wh[0][j] = 0;
    wh[1][j] = (unsigned short)a0;
    wh[2][j] = (unsigned short)(a0 + a1);
    wh[3][j] = (unsigned short)(a0 + a1 + a2);
  }
  __syncthreads();
  const int* ht = hist + (size_t)t * HB;            // scanned: global bin starts
#pragma unroll
  for (int c = 0; c < NCH; ++c) {
    int b = lb[c];
    if (b == 4095) continue;
    int rank = ht[b] + (int)wh[wv][b] + (int)lr[c];
    if (rank < MAXP) {
      int s = soh[b];
      if (s >= 0) {
        int i = sb + c * 64 + lane;
        size_t dst = (size_t)(s * MAXP + rank) * 5;
        size_t src = (size_t)i * 5;
        out[dst + 0] = pts[src + 0];
        out[dst + 1] = pts[src + 1];
        out[dst + 2] = pts[src + 2];
        out[dst + 3] = pts[src + 3];
        out[dst + 4] = pts[src + 4];
      }
    }
  }
}

// ---- pass 4 (generic fallback, any tile): round-1 shfl-based scatter ----
__global__ void k_scatter_gen(const float* __restrict__ pts, int N, int tile,
                              const int* __restrict__ hist,
                              const unsigned short* __restrict__ bins,
                              const int* __restrict__ soh,
                              float* __restrict__ out) {
  __shared__ int cur[HB];
  int t = blockIdx.x;
  int tid = threadIdx.x;
  for (int i = tid; i < HB; i += BLK) cur[i] = hist[(size_t)t * HB + i];
  __syncthreads();
  int base = t * tile;
  int end  = min(base + tile, N);
  int lane = tid & 63, wv = tid >> 6;
  for (int g = base; g < base + tile; g += BLK) {
    int i = g + tid;
    bool act = (i < end);
    int b = act ? (int)bins[i] : 0x10000;
    int rho = 0, kap = 0;
    for (int j = 0; j < 64; ++j) {
      int bj = __shfl(b, j, 64);
      if (bj == b) { kap++; if (j < lane) rho++; }
    }
    int rank = 0x7FFFFFFF;
    for (int w = 0; w < 4; ++w) {
      if (wv == w && act) {
        int bs = cur[b];
        rank = bs + rho;
        if (rho == 0) cur[b] = bs + kap;
      }
      __syncthreads();
    }
    if (act && rank < MAXP && b < HV) {
      int s = soh[b];
      if (s >= 0) {
        size_t dst = (size_t)(s * MAXP + rank) * 5;
        size_t src = (size_t)i * 5;
        out[dst + 0] = pts[src + 0];
        out[dst + 1] = pts[src + 1];
        out[dst + 2] = pts[src + 2];
        out[dst + 3] = pts[src + 3];
        out[dst + 4] = pts[src + 4];
      }
    }
  }
}

extern "C" void kernel_launch(void* const* d_in, const int* in_sizes, int n_in,
                              void* d_out, int out_size, void* d_ws, size_t ws_size,
                              hipStream_t stream) {
  const float* pts = (const float*)d_in[0];
  int N = in_sizes[0] / 5;
  float* out = (float*)d_out;

  auto align = [](size_t x) { return (x + 255) & ~(size_t)255; };
  int tile = TILE, NT = 1, NC = 1;
  for (;;) {
    NT = (N + tile - 1) / tile;
    NC = (NT + CHT - 1) / CHT;
    size_t o_hist = 0;
    size_t o_part = align(o_hist + (size_t)NT * HB * 4);
    size_t o_cnts = align(o_part + (size_t)NC * HB * 4);
    size_t o_soh  = align(o_cnts + (size_t)HB * 4);
    size_t o_s2h  = align(o_soh + (size_t)HV * 4);
    size_t o_bins = align(o_s2h + (size_t)MAXV * 4);
    size_t need   = o_bins + (size_t)N * 2;
    if (need <= ws_size || tile >= (1 << 22)) break;
    tile <<= 1;
  }
  size_t o_hist = 0;
  size_t o_part = align(o_hist + (size_t)NT * HB * 4);
  size_t o_cnts = align(o_part + (size_t)NC * HB * 4);
  size_t o_soh  = align(o_cnts + (size_t)HB * 4);
  size_t o_s2h  = align(o_soh + (size_t)HV * 4);
  size_t o_bins = align(o_s2h + (size_t)MAXV * 4);

  char* w = (char*)d_ws;
  int* hist = (int*)(w + o_hist);
  int* part = (int*)(w + o_part);
  int* cnts = (int*)(w + o_cnts);
  int* soh  = (int*)(w + o_soh);
  int* s2h  = (int*)(w + o_s2h);
  unsigned short* bins = (unsigned short*)(w + o_bins);

  hipMemsetAsync(d_out, 0, (size_t)out_size * 4, stream);
  k_hist<<<NT, BLK, 0, stream>>>(pts, N, tile, hist, bins);
  dim3 ga((HB + BLK - 1) / BLK, NC);
  k_scan_a<<<ga, BLK, 0, stream>>>(hist, NT, part);
  k_scan_b<<<(HB + BLK - 1) / BLK, BLK, 0, stream>>>(part, NC, cnts);
  k_slots<<<1, BLK, 0, stream>>>(cnts, soh, s2h);
  k_centers<<<(MAXV + BLK - 1) / BLK, BLK, 0, stream>>>(s2h, cnts, out);
  k_scan_c<<<ga, BLK, 0, stream>>>(hist, NT, part);
  if (tile == TILE) {
    k_scatter_fast<<<NT, BLK, 0, stream>>>(pts, N, hist, bins, soh, out);
  } else {
    k_scatter_gen<<<NT, BLK, 0, stream>>>(pts, N, tile, hist, bins, soh, out);
  }
}

// Round 3
// 96.134 us; speedup vs baseline: 1.3629x; 1.0057x over previous
//
#include <hip/hip_runtime.h>
#include <math.h>

// ---- problem constants ----
#define NRAD 48
#define NANG 72
#define HV   3456            // valid hashes = NRAD*NANG
#define HB   3457            // + invalid bin
#define MAXP 64
#define MAXV 3000
#define BLK  256
#define CHT  64              // tiles per scan chunk
#define TILE 4096
#define SUBT 1024            // per-wave sub-tile in fast scatter (TILE/4)
#define NCH  16              // chunks per sub-tile (SUBT/64)

// output layout (floats)
#define OFF_C   (MAXV*MAXP*5)          // 960000
#define OFF_N   (OFF_C + MAXV*3)       // 969000
#define OFF_X   (OFF_N + MAXV)         // 972000

#define PI_F 3.14159265358979323846f   // rounds to 0x40490FDB

// np.linspace(-pi, pi, 73) in f64 (y = i*step + start, endpoint forced), cast f32.
__device__ __forceinline__ float angle_edge(int j) {
  const double PI = 3.14159265358979311599796346854;
  const double step = (PI - (-PI)) / 72.0;
  if (j == 72) return (float)PI;
  return (float)(-PI + (double)j * step);
}

// ---- pass 0: fast zero of d_out (runtime fillBuffer runs 3.9MB at 82 GB/s; this
// grid-strided float4 kernel does it at HBM rate) ----
__global__ void k_zero(float4* __restrict__ o4, int n4) {
  int i = blockIdx.x * BLK + threadIdx.x;
  int stride = gridDim.x * BLK;
  for (; i < n4; i += stride) o4[i] = make_float4(0.f, 0.f, 0.f, 0.f);
}

// ---- pass 1: per-tile histogram + bin cache ----
// Fast path: f32 octant-reduced atan estimate (|err| <~ 1.2e-6) decides the
// angular bin when the point is > GUARD from both bin edges; otherwise fall
// back to the exact (float)atan2(f64) path (bit-identical to reference).
__global__ void k_hist(const float* __restrict__ pts, int N, int tile,
                       int* __restrict__ hist, unsigned short* __restrict__ bins) {
  __shared__ int lh[HB];
  __shared__ float eang[73];
  int t = blockIdx.x;
  for (int i = threadIdx.x; i < HB; i += BLK) lh[i] = 0;
  if (threadIdx.x < 73) eang[threadIdx.x] = angle_edge(threadIdx.x);
  __syncthreads();
  int base = t * tile;
  int end  = min(base + tile, N);
  for (int i = base + (int)threadIdx.x; i < end; i += BLK) {
    size_t p = (size_t)i * 5;
    float x = pts[p], y = pts[p + 1], z = pts[p + 2];
    // r exactly as reference: mul,mul,add,sqrt in RN, no contraction
    float r = __fsqrt_rn(__fadd_rn(__fmul_rn(x, x), __fmul_rn(y, y)));
    int b = HV;
    if (z >= -3.0f && z < 5.0f && r >= 2.0f && r < 50.0f) {
      int ri = (int)ceilf(r) - 3;               // exact: edges are ints 2..50
      ri = max(0, min(NRAD - 1, ri));
      // --- fast theta estimate ---
      float ax = fabsf(x), ay = fabsf(y);
      float u = fminf(ax, ay), U = fmaxf(ax, ay);
      bool big = u > 0.41421356f * U;           // tan(pi/8); either branch valid at tie
      float num = big ? (U - u) : u;
      float den = big ? (U + u) : U;
      float v = num / den;                      // in [0, 0.41422]
      float s = v * v;
      float a = 0.05882353f;                    // 1/17
      a = a * s - 0.06666667f;                  // -1/15
      a = a * s + 0.07692308f;                  // 1/13
      a = a * s - 0.09090909f;                  // -1/11
      a = a * s + 0.11111111f;                  // 1/9
      a = a * s - 0.14285714f;                  // -1/7
      a = a * s + 0.2f;                         // 1/5
      a = a * s - 0.33333333f;                  // -1/3
      a = a * s + 1.0f;
      float pp = v * a;                         // atan(v)
      float th1 = big ? (0.78539816f - pp) : pp;
      if (ay > ax) th1 = 1.57079633f - th1;
      if (x < 0.0f) th1 = PI_F - th1;
      float that = copysignf(th1, y);
      // candidate bin via guess + fixup on the estimate
      int g = (int)floorf((that + PI_F) * 11.459155902616465f);
      g = max(0, min(NANG - 1, g));
      while (g > 0 && !(eang[g] < that)) g--;
      while (g < NANG - 1 && eang[g + 1] < that) g++;
      float d0 = that - eang[g];
      float d1 = eang[g + 1] - that;
      const float GUARD = 2e-5f;
      if (d0 > GUARD && d1 > GUARD) {
        b = ri * NANG + g;                      // far from edges: estimate decides
      } else {
        // --- exact path (rare): bit-identical to reference semantics ---
        float th = (float)atan2((double)y, (double)x);
        if (th >= eang[0] && th < eang[72]) {
          int gg = g;
          while (gg > 0 && !(eang[gg] < th)) gg--;
          while (gg < NANG - 1 && eang[gg + 1] < th) gg++;
          b = ri * NANG + max(0, min(NANG - 1, gg));
        } else {
          b = HV;
        }
      }
    }
    bins[i] = (unsigned short)b;
    atomicAdd(&lh[b], 1);
  }
  __syncthreads();
  int* ht = hist + (size_t)t * HB;
  for (int i = threadIdx.x; i < HB; i += BLK) ht[i] = lh[i];
}

// ---- pass 2: exclusive scan of hist across tiles, per bin (chunked 2-level) ----
__global__ void k_scan_a(const int* __restrict__ hist, int NT, int* __restrict__ part) {
  int b = blockIdx.x * BLK + threadIdx.x;
  int c = blockIdx.y;
  if (b >= HB) return;
  int t0 = c * CHT, t1 = min(t0 + CHT, NT);
  int s = 0;
  for (int t = t0; t < t1; ++t) s += hist[(size_t)t * HB + b];
  part[(size_t)c * HB + b] = s;
}

__global__ void k_scan_b(int* __restrict__ part, int NC, int* __restrict__ counts) {
  int b = blockIdx.x * BLK + threadIdx.x;
  if (b >= HB) return;
  int run = 0;
  for (int c = 0; c < NC; ++c) {
    size_t o = (size_t)c * HB + b;
    int v = part[o];
    part[o] = run;
    run += v;
  }
  counts[b] = run;
}

__global__ void k_scan_c(int* __restrict__ hist, int NT, const int* __restrict__ part) {
  int b = blockIdx.x * BLK + threadIdx.x;
  int c = blockIdx.y;
  if (b >= HB) return;
  int t0 = c * CHT, t1 = min(t0 + CHT, NT);
  int run = part[(size_t)c * HB + b];
  for (int t = t0; t < t1; ++t) {
    size_t o = (size_t)t * HB + b;
    int v = hist[o];
    hist[o] = run;
    run += v;
  }
}

// ---- pass 3a: slot assignment (single block scan over 3456 bins) ----
__global__ void k_slots(const int* __restrict__ counts, int* __restrict__ soh,
                        int* __restrict__ s2h) {
  __shared__ int ssum[BLK];
  const int PER = (HV + BLK - 1) / BLK;   // 14
  int tid = threadIdx.x;
  for (int i = tid; i < MAXV; i += BLK) s2h[i] = -1;
  int cnt[PER];
  int tsum = 0;
#pragma unroll
  for (int k = 0; k < PER; ++k) {
    int h = tid * PER + k;
    int c = (h < HV) ? counts[h] : 0;
    cnt[k] = c;
    tsum += (c > 0) ? 1 : 0;
  }
  ssum[tid] = tsum;
  __syncthreads();
  for (int off = 1; off < BLK; off <<= 1) {
    int v = (tid >= off) ? ssum[tid - off] : 0;
    __syncthreads();
    ssum[tid] += v;
    __syncthreads();
  }
  int run = ssum[tid] - tsum;   // exclusive base
#pragma unroll
  for (int k = 0; k < PER; ++k) {
    int h = tid * PER + k;
    if (h < HV) {
      int s = -1;
      if (cnt[k] > 0) {
        if (run < MAXV) s = run;
        run++;
      }
      soh[h] = s;
      if (s >= 0) s2h[s] = h;
    }
  }
}

// ---- pass 3b: coords / num_points / centers (parallel over slots) ----
__global__ void k_centers(const int* __restrict__ s2h, const int* __restrict__ counts,
                          float* __restrict__ out) {
  int s = blockIdx.x * BLK + threadIdx.x;
  if (s >= MAXV) return;
  int h = s2h[s];
  if (h < 0) return;
  int ri = h / NANG, ti = h % NANG;
  out[OFF_C + s * 3 + 0] = (float)ri;
  out[OFF_C + s * 3 + 1] = (float)ti;
  out[OFF_C + s * 3 + 2] = 0.0f;
  out[OFF_N + s] = (float)min(counts[h], MAXP);
  float rc = 2.5f + (float)ri;
  float e0 = angle_edge(ti), e1 = angle_edge(ti + 1);
  float tc = __fmul_rn(0.5f, __fadd_rn(e0, e1));
  out[OFF_X + s * 2 + 0] = __fmul_rn(rc, (float)cos((double)tc));
  out[OFF_X + s * 2 + 1] = __fmul_rn(rc, (float)sin((double)tc));
}

// ---- pass 4 (fast, tile==4096): ballot-rank scatter, barrier-free main loop ----
__global__ __launch_bounds__(BLK) void k_scatter_fast(
    const float* __restrict__ pts, int N,
    const int* __restrict__ hist, const unsigned short* __restrict__ bins,
    const int* __restrict__ soh, float* __restrict__ out) {
  __shared__ unsigned int whd[4 * HV / 2];          // 4 x HV u16 = 27648 B
  unsigned short (*wh)[HV] = (unsigned short (*)[HV])whd;
  int t = blockIdx.x;
  int tid = threadIdx.x;
  int lane = tid & 63, wv = tid >> 6;
  for (int i = tid; i < 4 * HV / 2; i += BLK) whd[i] = 0u;
  __syncthreads();
  int base = t * TILE;
  int end  = min(base + TILE, N);
  int sb = base + wv * SUBT;
  int se = min(sb + SUBT, end);
  unsigned short lb[NCH], lr[NCH];
  const unsigned long long lmask = (1ULL << lane) - 1ULL;
#pragma unroll
  for (int c = 0; c < NCH; ++c) {
    int i = sb + c * 64 + lane;
    int b = 4095;                                   // sentinel (> any real bin)
    if (i < se) { int bi = bins[i]; if (bi < HV) b = bi; }
    unsigned long long m = ~0ULL;
#pragma unroll
    for (int k = 0; k < 12; ++k) {
      unsigned long long bal = __ballot((b >> k) & 1);
      m &= ((b >> k) & 1) ? bal : ~bal;
    }
    int rho = __popcll(m & lmask);                  // same-bin lanes before me
    int kap = __popcll(m);                          // same-bin lanes in chunk
    int cv = 0;
    if (b != 4095) {
      cv = wh[wv][b];                               // read before leader write
      if (rho == 0) wh[wv][b] = (unsigned short)(cv + kap);
    }
    lb[c] = (unsigned short)b;
    lr[c] = (unsigned short)(cv + rho);
  }
  __syncthreads();
  // column prefix across waves: wh[w][j] <- sum_{w'<w} counts
  for (int j = tid; j < HV; j += BLK) {
    int a0 = wh[0][j], a1 = wh[1][j], a2 = wh[2][j];
    wh[0][j] = 0;
    wh[1][j] = (unsigned short)a0;
    wh[2][j] = (unsigned short)(a0 + a1);
    wh[3][j] = (unsigned short)(a0 + a1 + a2);
  }
  __syncthreads();
  const int* ht = hist + (size_t)t * HB;            // scanned: global bin starts
#pragma unroll
  for (int c = 0; c < NCH; ++c) {
    int b = lb[c];
    if (b == 4095) continue;
    int rank = ht[b] + (int)wh[wv][b] + (int)lr[c];
    if (rank < MAXP) {
      int s = soh[b];
      if (s >= 0) {
        int i = sb + c * 64 + lane;
        size_t dst = (size_t)(s * MAXP + rank) * 5;
        size_t src = (size_t)i * 5;
        out[dst + 0] = pts[src + 0];
        out[dst + 1] = pts[src + 1];
        out[dst + 2] = pts[src + 2];
        out[dst + 3] = pts[src + 3];
        out[dst + 4] = pts[src + 4];
      }
    }
  }
}

// ---- pass 4 (generic fallback, any tile): shfl-based scatter ----
__global__ void k_scatter_gen(const float* __restrict__ pts, int N, int tile,
                              const int* __restrict__ hist,
                              const unsigned short* __restrict__ bins,
                              const int* __restrict__ soh,
                              float* __restrict__ out) {
  __shared__ int cur[HB];
  int t = blockIdx.x;
  int tid = threadIdx.x;
  for (int i = tid; i < HB; i += BLK) cur[i] = hist[(size_t)t * HB + i];
  __syncthreads();
  int base = t * tile;
  int end  = min(base + tile, N);
  int lane = tid & 63, wv = tid >> 6;
  for (int g = base; g < base + tile; g += BLK) {
    int i = g + tid;
    bool act = (i < end);
    int b = act ? (int)bins[i] : 0x10000;
    int rho = 0, kap = 0;
    for (int j = 0; j < 64; ++j) {
      int bj = __shfl(b, j, 64);
      if (bj == b) { kap++; if (j < lane) rho++; }
    }
    int rank = 0x7FFFFFFF;
    for (int w = 0; w < 4; ++w) {
      if (wv == w && act) {
        int bs = cur[b];
        rank = bs + rho;
        if (rho == 0) cur[b] = bs + kap;
      }
      __syncthreads();
    }
    if (act && rank < MAXP && b < HV) {
      int s = soh[b];
      if (s >= 0) {
        size_t dst = (size_t)(s * MAXP + rank) * 5;
        size_t src = (size_t)i * 5;
        out[dst + 0] = pts[src + 0];
        out[dst + 1] = pts[src + 1];
        out[dst + 2] = pts[src + 2];
        out[dst + 3] = pts[src + 3];
        out[dst + 4] = pts[src + 4];
      }
    }
  }
}

extern "C" void kernel_launch(void* const* d_in, const int* in_sizes, int n_in,
                              void* d_out, int out_size, void* d_ws, size_t ws_size,
                              hipStream_t stream) {
  const float* pts = (const float*)d_in[0];
  int N = in_sizes[0] / 5;
  float* out = (float*)d_out;

  auto align = [](size_t x) { return (x + 255) & ~(size_t)255; };
  int tile = TILE, NT = 1, NC = 1;
  for (;;) {
    NT = (N + tile - 1) / tile;
    NC = (NT + CHT - 1) / CHT;
    size_t o_hist = 0;
    size_t o_part = align(o_hist + (size_t)NT * HB * 4);
    size_t o_cnts = align(o_part + (size_t)NC * HB * 4);
    size_t o_soh  = align(o_cnts + (size_t)HB * 4);
    size_t o_s2h  = align(o_soh + (size_t)HV * 4);
    size_t o_bins = align(o_s2h + (size_t)MAXV * 4);
    size_t need   = o_bins + (size_t)N * 2;
    if (need <= ws_size || tile >= (1 << 22)) break;
    tile <<= 1;
  }
  size_t o_hist = 0;
  size_t o_part = align(o_hist + (size_t)NT * HB * 4);
  size_t o_cnts = align(o_part + (size_t)NC * HB * 4);
  size_t o_soh  = align(o_cnts + (size_t)HB * 4);
  size_t o_s2h  = align(o_soh + (size_t)HV * 4);
  size_t o_bins = align(o_s2h + (size_t)MAXV * 4);

  char* w = (char*)d_ws;
  int* hist = (int*)(w + o_hist);
  int* part = (int*)(w + o_part);
  int* cnts = (int*)(w + o_cnts);
  int* soh  = (int*)(w + o_soh);
  int* s2h  = (int*)(w + o_s2h);
  unsigned short* bins = (unsigned short*)(w + o_bins);

  // fast zero of d_out (out_size floats); float4 main + scalar tail
  {
    int n4 = out_size / 4;
    int tail = out_size - n4 * 4;
    int blocks = min((n4 + BLK - 1) / BLK, 2048);
    if (n4 > 0) k_zero<<<blocks, BLK, 0, stream>>>((float4*)out, n4);
    if (tail > 0) hipMemsetAsync((char*)out + (size_t)n4 * 16, 0, (size_t)tail * 4, stream);
  }
  k_hist<<<NT, BLK, 0, stream>>>(pts, N, tile, hist, bins);
  dim3 ga((HB + BLK - 1) / BLK, NC);
  k_scan_a<<<ga, BLK, 0, stream>>>(hist, NT, part);
  k_scan_b<<<(HB + BLK - 1) / BLK, BLK, 0, stream>>>(part, NC, cnts);
  k_slots<<<1, BLK, 0, stream>>>(cnts, soh, s2h);
  k_centers<<<(MAXV + BLK - 1) / BLK, BLK, 0, stream>>>(s2h, cnts, out);
  k_scan_c<<<ga, BLK, 0, stream>>>(hist, NT, part);
  if (tile == TILE) {
    k_scatter_fast<<<NT, BLK, 0, stream>>>(pts, N, hist, bins, soh, out);
  } else {
    k_scatter_gen<<<NT, BLK, 0, stream>>>(pts, N, tile, hist, bins, soh, out);
  }
}

// Round 4
// 93.052 us; speedup vs baseline: 1.4081x; 1.0331x over previous
//
#include <hip/hip_runtime.h>
#include <math.h>

// ---- problem constants ----
#define NRAD 48
#define NANG 72
#define HV   3456            // valid hashes = NRAD*NANG
#define HVW  864             // HV/4 (u32 words of packed u8 counters)
#define MAXP 64
#define MAXV 3000
#define BLK  256
#define CHT  64              // tiles per scan chunk
#define TILE 4096
#define SUBT 1024            // per-wave sub-tile in fast scatter (TILE/4)
#define NCH  16              // chunks per sub-tile (SUBT/64)

// output layout (floats)
#define OFF_C   (MAXV*MAXP*5)          // 960000
#define OFF_N   (OFF_C + MAXV*3)       // 969000
#define OFF_X   (OFF_N + MAXV)         // 972000

#define PI_F 3.14159265358979323846f   // rounds to 0x40490FDB

// np.linspace(-pi, pi, 73) in f64 (y = i*step + start, endpoint forced), cast f32.
__device__ __forceinline__ float angle_edge(int j) {
  const double PI = 3.14159265358979311599796346854;
  const double step = (PI - (-PI)) / 72.0;
  if (j == 72) return (float)PI;
  return (float)(-PI + (double)j * step);
}

// ---- pass 1: zero d_out + per-tile saturated u8 histogram + bin cache ----
// All counts saturate at 64: ranks >=64 are dropped and num_points=min(c,64),
// so saturating arithmetic is exact wherever it matters (any clamped addend
// forces the true prefix >=64 as well).
__global__ __launch_bounds__(BLK) void k_hist(
    const float* __restrict__ pts, int N, int tile, int n4, int tailN,
    unsigned char* __restrict__ hist, unsigned short* __restrict__ bins,
    float4* __restrict__ out4) {
  __shared__ int lh[HV];
  __shared__ float eang[73];
  int t = blockIdx.x, tid = threadIdx.x;
  // fused zero of d_out (grid-strided float4; runs in parallel with binning setup)
  for (int j = t * BLK + tid; j < n4; j += gridDim.x * BLK)
    out4[j] = make_float4(0.f, 0.f, 0.f, 0.f);
  if (t == 0 && tid < tailN) ((float*)out4)[(size_t)n4 * 4 + tid] = 0.f;
  for (int i = tid; i < HV; i += BLK) lh[i] = 0;
  if (tid < 73) eang[tid] = angle_edge(tid);
  __syncthreads();
  int base = t * tile;
  int end  = min(base + tile, N);
  for (int i = base + tid; i < end; i += BLK) {
    size_t p = (size_t)i * 5;
    float x = pts[p], y = pts[p + 1], z = pts[p + 2];
    // r exactly as reference: mul,mul,add,sqrt in RN, no contraction
    float r = __fsqrt_rn(__fadd_rn(__fmul_rn(x, x), __fmul_rn(y, y)));
    int b = HV;
    if (z >= -3.0f && z < 5.0f && r >= 2.0f && r < 50.0f) {
      int ri = (int)ceilf(r) - 3;               // exact: edges are ints 2..50
      ri = max(0, min(NRAD - 1, ri));
      // --- fast theta estimate (|err| <~ 1.2e-6) ---
      float ax = fabsf(x), ay = fabsf(y);
      float u = fminf(ax, ay), U = fmaxf(ax, ay);
      bool big = u > 0.41421356f * U;           // tan(pi/8); either branch valid at tie
      float num = big ? (U - u) : u;
      float den = big ? (U + u) : U;
      float v = num / den;                      // in [0, 0.41422]
      float s = v * v;
      float a = 0.05882353f;
      a = a * s - 0.06666667f;
      a = a * s + 0.07692308f;
      a = a * s - 0.09090909f;
      a = a * s + 0.11111111f;
      a = a * s - 0.14285714f;
      a = a * s + 0.2f;
      a = a * s - 0.33333333f;
      a = a * s + 1.0f;
      float pp = v * a;                         // atan(v)
      float th1 = big ? (0.78539816f - pp) : pp;
      if (ay > ax) th1 = 1.57079633f - th1;
      if (x < 0.0f) th1 = PI_F - th1;
      float that = copysignf(th1, y);
      int g = (int)floorf((that + PI_F) * 11.459155902616465f);
      g = max(0, min(NANG - 1, g));
      while (g > 0 && !(eang[g] < that)) g--;
      while (g < NANG - 1 && eang[g + 1] < that) g++;
      float d0 = that - eang[g];
      float d1 = eang[g + 1] - that;
      const float GUARD = 2e-5f;
      if (d0 > GUARD && d1 > GUARD) {
        b = ri * NANG + g;                      // far from edges: estimate decides
      } else {
        // --- exact path (rare): bit-identical to reference semantics ---
        float th = (float)atan2((double)y, (double)x);
        if (th >= eang[0] && th < eang[72]) {
          int gg = g;
          while (gg > 0 && !(eang[gg] < th)) gg--;
          while (gg < NANG - 1 && eang[gg + 1] < th) gg++;
          b = ri * NANG + max(0, min(NANG - 1, gg));
        } else {
          b = HV;
        }
      }
    }
    bins[i] = (unsigned short)b;
    if (b < HV) atomicAdd(&lh[b], 1);
  }
  __syncthreads();
  unsigned char* ht = hist + (size_t)t * HV;
  for (int i = tid; i < HV; i += BLK) ht[i] = (unsigned char)min(lh[i], 64);
}

// ---- pass 2a: per-chunk saturated sums (u32-packed u8 lanes) ----
__global__ void k_scan_a(const unsigned int* __restrict__ hist32, int NT,
                         unsigned int* __restrict__ part32) {
  int w = blockIdx.x * BLK + threadIdx.x;     // word 0..HVW-1 (4 bins per word)
  int c = blockIdx.y;
  if (w >= HVW) return;
  int t0 = c * CHT, t1 = min(t0 + CHT, NT);
  int s0 = 0, s1 = 0, s2 = 0, s3 = 0;
  for (int t = t0; t < t1; ++t) {
    unsigned int v = hist32[(size_t)t * HVW + w];
    s0 = min(s0 + (int)(v & 255u), 64);
    s1 = min(s1 + (int)((v >> 8) & 255u), 64);
    s2 = min(s2 + (int)((v >> 16) & 255u), 64);
    s3 = min(s3 + (int)(v >> 24), 64);
  }
  part32[(size_t)c * HVW + w] = (unsigned)s0 | ((unsigned)s1 << 8) |
                                ((unsigned)s2 << 16) | ((unsigned)s3 << 24);
}

// ---- pass 2b fused: chunk-exclusive scan + slot assignment + coords/num/centers ----
__global__ __launch_bounds__(1024) void k_bsc(unsigned int* __restrict__ part32, int NC,
                                              int* __restrict__ soh,
                                              float* __restrict__ out) {
  __shared__ float eang[73];
  __shared__ int ssum[1024];
  int tid = threadIdx.x;
  if (tid < 73) eang[tid] = angle_edge(tid);
  int c0 = 0, c1 = 0, c2 = 0, c3 = 0;
  if (tid < HVW) {
    int r0 = 0, r1 = 0, r2 = 0, r3 = 0;
    for (int c = 0; c < NC; ++c) {
      size_t o = (size_t)c * HVW + tid;
      unsigned int v = part32[o];
      part32[o] = (unsigned)r0 | ((unsigned)r1 << 8) |
                  ((unsigned)r2 << 16) | ((unsigned)r3 << 24);
      r0 = min(r0 + (int)(v & 255u), 64);
      r1 = min(r1 + (int)((v >> 8) & 255u), 64);
      r2 = min(r2 + (int)((v >> 16) & 255u), 64);
      r3 = min(r3 + (int)(v >> 24), 64);
    }
    c0 = r0; c1 = r1; c2 = r2; c3 = r3;
  }
  int occ = (c0 > 0) + (c1 > 0) + (c2 > 0) + (c3 > 0);
  ssum[tid] = occ;
  __syncthreads();
  for (int off = 1; off < 1024; off <<= 1) {
    int v = (tid >= off) ? ssum[tid - off] : 0;
    __syncthreads();
    ssum[tid] += v;
    __syncthreads();
  }
  int base = ssum[tid] - occ;                 // exclusive slot base (bin order)
  if (tid < HVW) {
    int cs[4] = {c0, c1, c2, c3};
#pragma unroll
    for (int k = 0; k < 4; ++k) {
      int h = tid * 4 + k;
      int cnt = cs[k];
      int s = -1;
      if (cnt > 0) {
        if (base < MAXV) s = base;
        base++;
      }
      soh[h] = s;
      if (s >= 0) {
        int ri = h / NANG, ti = h % NANG;
        out[OFF_C + s * 3 + 0] = (float)ri;
        out[OFF_C + s * 3 + 1] = (float)ti;
        out[OFF_C + s * 3 + 2] = 0.0f;
        out[OFF_N + s] = (float)cnt;          // cnt already saturated at 64
        float rc = 2.5f + (float)ri;
        float tc = 0.5f * (eang[ti] + eang[ti + 1]);
        out[OFF_X + s * 2 + 0] = rc * cosf(tc);   // ~5e-5 abs err << threshold
        out[OFF_X + s * 2 + 1] = rc * sinf(tc);
      }
    }
  }
}

// ---- pass 2c: in-place exclusive tile-start scan within each chunk (saturated) ----
__global__ void k_scan_c(unsigned int* __restrict__ hist32, int NT,
                         const unsigned int* __restrict__ part32) {
  int w = blockIdx.x * BLK + threadIdx.x;
  int c = blockIdx.y;
  if (w >= HVW) return;
  int t0 = c * CHT, t1 = min(t0 + CHT, NT);
  unsigned int pv = part32[(size_t)c * HVW + w];
  int r0 = pv & 255u, r1 = (pv >> 8) & 255u, r2 = (pv >> 16) & 255u, r3 = pv >> 24;
  for (int t = t0; t < t1; ++t) {
    size_t o = (size_t)t * HVW + w;
    unsigned int v = hist32[o];
    hist32[o] = (unsigned)r0 | ((unsigned)r1 << 8) |
                ((unsigned)r2 << 16) | ((unsigned)r3 << 24);
    r0 = min(r0 + (int)(v & 255u), 64);
    r1 = min(r1 + (int)((v >> 8) & 255u), 64);
    r2 = min(r2 + (int)((v >> 16) & 255u), 64);
    r3 = min(r3 + (int)(v >> 24), 64);
  }
}

// ---- pass 3 (fast, tile==4096): ballot-rank scatter, barrier-free main loop ----
__global__ __launch_bounds__(BLK) void k_scatter_fast(
    const float* __restrict__ pts, int N,
    const unsigned char* __restrict__ hist, const unsigned short* __restrict__ bins,
    const int* __restrict__ soh, float* __restrict__ out) {
  __shared__ unsigned int whd[4 * HV / 2];          // 4 x HV u16 = 27648 B
  unsigned short (*wh)[HV] = (unsigned short (*)[HV])whd;
  int t = blockIdx.x;
  int tid = threadIdx.x;
  int lane = tid & 63, wv = tid >> 6;
  for (int i = tid; i < 4 * HV / 2; i += BLK) whd[i] = 0u;
  __syncthreads();
  int base = t * TILE;
  int end  = min(base + TILE, N);
  int sb = base + wv * SUBT;
  int se = min(sb + SUBT, end);
  unsigned short lb[NCH], lr[NCH];
  const unsigned long long lmask = (1ULL << lane) - 1ULL;
#pragma unroll
  for (int c = 0; c < NCH; ++c) {
    int i = sb + c * 64 + lane;
    int b = 4095;                                   // sentinel (> any real bin)
    if (i < se) { int bi = bins[i]; if (bi < HV) b = bi; }
    unsigned long long m = ~0ULL;
#pragma unroll
    for (int k = 0; k < 12; ++k) {
      unsigned long long bal = __ballot((b >> k) & 1);
      m &= ((b >> k) & 1) ? bal : ~bal;
    }
    int rho = __popcll(m & lmask);                  // same-bin lanes before me
    int kap = __popcll(m);                          // same-bin lanes in chunk
    int cv = 0;
    if (b != 4095) {
      cv = wh[wv][b];                               // read before leader write
      if (rho == 0) wh[wv][b] = (unsigned short)(cv + kap);
    }
    lb[c] = (unsigned short)b;
    lr[c] = (unsigned short)(cv + rho);
  }
  __syncthreads();
  for (int j = tid; j < HV; j += BLK) {
    int a0 = wh[0][j], a1 = wh[1][j], a2 = wh[2][j];
    wh[0][j] = 0;
    wh[1][j] = (unsigned short)a0;
    wh[2][j] = (unsigned short)(a0 + a1);
    wh[3][j] = (unsigned short)(a0 + a1 + a2);
  }
  __syncthreads();
  const unsigned char* ht = hist + (size_t)t * HV;  // saturated tile-start offsets
#pragma unroll
  for (int c = 0; c < NCH; ++c) {
    int b = lb[c];
    if (b == 4095) continue;
    int rank = (int)ht[b] + (int)wh[wv][b] + (int)lr[c];
    if (rank < MAXP) {
      int s = soh[b];
      if (s >= 0) {
        int i = sb + c * 64 + lane;
        size_t dst = (size_t)(s * MAXP + rank) * 5;
        size_t src = (size_t)i * 5;
        out[dst + 0] = pts[src + 0];
        out[dst + 1] = pts[src + 1];
        out[dst + 2] = pts[src + 2];
        out[dst + 3] = pts[src + 3];
        out[dst + 4] = pts[src + 4];
      }
    }
  }
}

// ---- pass 3 (generic fallback, any tile) ----
__global__ void k_scatter_gen(const float* __restrict__ pts, int N, int tile,
                              const unsigned char* __restrict__ hist,
                              const unsigned short* __restrict__ bins,
                              const int* __restrict__ soh,
                              float* __restrict__ out) {
  __shared__ int cur[HV + 1];
  int t = blockIdx.x;
  int tid = threadIdx.x;
  const unsigned char* ht = hist + (size_t)t * HV;
  for (int i = tid; i < HV + 1; i += BLK) cur[i] = (i < HV) ? (int)ht[i] : 0;
  __syncthreads();
  int base = t * tile;
  int end  = min(base + tile, N);
  int lane = tid & 63, wv = tid >> 6;
  for (int g = base; g < base + tile; g += BLK) {
    int i = g + tid;
    bool act = (i < end);
    int b = act ? (int)bins[i] : 0x10000;
    int rho = 0, kap = 0;
    for (int j = 0; j < 64; ++j) {
      int bj = __shfl(b, j, 64);
      if (bj == b) { kap++; if (j < lane) rho++; }
    }
    int rank = 0x7FFFFFFF;
    for (int w = 0; w < 4; ++w) {
      if (wv == w && act) {
        int bs = cur[b];
        rank = bs + rho;
        if (rho == 0) cur[b] = bs + kap;
      }
      __syncthreads();
    }
    if (act && rank < MAXP && b < HV) {
      int s = soh[b];
      if (s >= 0) {
        size_t dst = (size_t)(s * MAXP + rank) * 5;
        size_t src = (size_t)i * 5;
        out[dst + 0] = pts[src + 0];
        out[dst + 1] = pts[src + 1];
        out[dst + 2] = pts[src + 2];
        out[dst + 3] = pts[src + 3];
        out[dst + 4] = pts[src + 4];
      }
    }
  }
}

extern "C" void kernel_launch(void* const* d_in, const int* in_sizes, int n_in,
                              void* d_out, int out_size, void* d_ws, size_t ws_size,
                              hipStream_t stream) {
  const float* pts = (const float*)d_in[0];
  int N = in_sizes[0] / 5;
  float* out = (float*)d_out;

  auto align = [](size_t x) { return (x + 255) & ~(size_t)255; };
  int tile = TILE, NT = 1, NC = 1;
  size_t o_hist = 0, o_part = 0, o_soh = 0, o_bins = 0;
  for (;;) {
    NT = (N + tile - 1) / tile;
    NC = (NT + CHT - 1) / CHT;
    o_hist = 0;
    o_part = align(o_hist + (size_t)NT * HV);
    o_soh  = align(o_part + (size_t)NC * HV);
    o_bins = align(o_soh + (size_t)HV * 4);
    size_t need = o_bins + (size_t)N * 2;
    if (need <= ws_size || tile >= (1 << 22)) break;
    tile <<= 1;
  }

  char* w = (char*)d_ws;
  unsigned char* hist = (unsigned char*)(w + o_hist);
  unsigned int*  hist32 = (unsigned int*)hist;
  unsigned int*  part32 = (unsigned int*)(w + o_part);
  int* soh = (int*)(w + o_soh);
  unsigned short* bins = (unsigned short*)(w + o_bins);

  int n4 = out_size / 4;
  int tailN = out_size - n4 * 4;

  k_hist<<<NT, BLK, 0, stream>>>(pts, N, tile, n4, tailN, hist, bins, (float4*)out);
  dim3 ga((HVW + BLK - 1) / BLK, NC);
  k_scan_a<<<ga, BLK, 0, stream>>>(hist32, NT, part32);
  k_bsc<<<1, 1024, 0, stream>>>(part32, NC, soh, out);
  k_scan_c<<<ga, BLK, 0, stream>>>(hist32, NT, part32);
  if (tile == TILE) {
    k_scatter_fast<<<NT, BLK, 0, stream>>>(pts, N, hist, bins, soh, out);
  } else {
    k_scatter_gen<<<NT, BLK, 0, stream>>>(pts, N, tile, hist, bins, soh, out);
  }
}

// Round 5
// 92.002 us; speedup vs baseline: 1.4242x; 1.0114x over previous
//
#include <hip/hip_runtime.h>
#include <math.h>

// ---- problem constants ----
#define NRAD 48
#define NANG 72
#define HV   3456            // valid hashes = NRAD*NANG
#define HVW  864             // HV/4 (u32 words of packed u8 counters)
#define MAXP 64
#define MAXV 3000
#define BLK  256
#define CHT  64              // tiles per scan chunk
#define TILE 4096
#define SUBT 1024            // per-wave sub-tile in fast scatter (TILE/4)
#define NCH  16              // chunks per sub-tile (SUBT/64)

// output layout (floats)
#define OFF_C   (MAXV*MAXP*5)          // 960000
#define OFF_N   (OFF_C + MAXV*3)       // 969000
#define OFF_X   (OFF_N + MAXV)         // 972000

#define PI_F 3.14159265358979323846f   // rounds to 0x40490FDB

// np.linspace(-pi, pi, 73) in f64 (y = i*step + start, endpoint forced), cast f32.
__device__ __forceinline__ float angle_edge(int j) {
  const double PI = 3.14159265358979311599796346854;
  const double step = (PI - (-PI)) / 72.0;
  if (j == 72) return (float)PI;
  return (float)(-PI + (double)j * step);
}

// bin per reference semantics; fast f32 atan estimate decides unless within
// GUARD of an edge, then exact (float)atan2(f64) fallback (bit-identical).
__device__ __forceinline__ int point_bin(float x, float y, float z,
                                         const float* __restrict__ eang) {
  float r = __fsqrt_rn(__fadd_rn(__fmul_rn(x, x), __fmul_rn(y, y)));
  if (!(z >= -3.0f && z < 5.0f && r >= 2.0f && r < 50.0f)) return HV;
  int ri = (int)ceilf(r) - 3;                 // exact: edges are ints 2..50
  ri = max(0, min(NRAD - 1, ri));
  float ax = fabsf(x), ay = fabsf(y);
  float u = fminf(ax, ay), U = fmaxf(ax, ay);
  bool big = u > 0.41421356f * U;             // tan(pi/8); either branch valid at tie
  float num = big ? (U - u) : u;
  float den = big ? (U + u) : U;
  float v = num / den;                        // in [0, 0.41422]
  float s = v * v;
  float a = 0.05882353f;
  a = a * s - 0.06666667f;
  a = a * s + 0.07692308f;
  a = a * s - 0.09090909f;
  a = a * s + 0.11111111f;
  a = a * s - 0.14285714f;
  a = a * s + 0.2f;
  a = a * s - 0.33333333f;
  a = a * s + 1.0f;
  float pp = v * a;                           // atan(v)
  float th1 = big ? (0.78539816f - pp) : pp;
  if (ay > ax) th1 = 1.57079633f - th1;
  if (x < 0.0f) th1 = PI_F - th1;
  float that = copysignf(th1, y);
  int g = (int)floorf((that + PI_F) * 11.459155902616465f);
  g = max(0, min(NANG - 1, g));
  while (g > 0 && !(eang[g] < that)) g--;
  while (g < NANG - 1 && eang[g + 1] < that) g++;
  float d0 = that - eang[g];
  float d1 = eang[g + 1] - that;
  const float GUARD = 2e-5f;
  if (d0 > GUARD && d1 > GUARD) return ri * NANG + g;
  // exact path (rare)
  float th = (float)atan2((double)y, (double)x);
  if (!(th >= eang[0] && th < eang[72])) return HV;
  int gg = g;
  while (gg > 0 && !(eang[gg] < th)) gg--;
  while (gg < NANG - 1 && eang[gg + 1] < th) gg++;
  return ri * NANG + max(0, min(NANG - 1, gg));
}

// ---- pass 1: zero d_out + per-tile saturated u8 histogram + bin cache ----
// 4 points/thread via five float4 loads (20 floats = 4 points), ushort4 bins store.
__global__ __launch_bounds__(BLK) void k_hist(
    const float* __restrict__ pts, int N, int tile, int n4, int tailN,
    unsigned char* __restrict__ hist, unsigned short* __restrict__ bins,
    float4* __restrict__ out4) {
  __shared__ int lh[HV];
  __shared__ float eang[73];
  int t = blockIdx.x, tid = threadIdx.x;
  for (int j = t * BLK + tid; j < n4; j += gridDim.x * BLK)
    out4[j] = make_float4(0.f, 0.f, 0.f, 0.f);
  if (t == 0 && tid < tailN) ((float*)out4)[(size_t)n4 * 4 + tid] = 0.f;
  for (int i = tid; i < HV; i += BLK) lh[i] = 0;
  if (tid < 73) eang[tid] = angle_edge(tid);
  __syncthreads();
  int base = t * tile;
  int end  = min(base + tile, N);
  int endq = base + (((end - base) >> 2) << 2);
  const float4* p4 = (const float4*)pts;
  for (int i0 = base + (tid << 2); i0 < endq; i0 += (BLK << 2)) {
    size_t q = (size_t)(i0 >> 2) * 5;
    float4 v0 = p4[q], v1 = p4[q + 1], v2 = p4[q + 2], v3 = p4[q + 3], v4 = p4[q + 4];
    int b0 = point_bin(v0.x, v0.y, v0.z, eang);
    int b1 = point_bin(v1.y, v1.z, v1.w, eang);
    int b2 = point_bin(v2.z, v2.w, v3.x, eang);
    int b3 = point_bin(v3.w, v4.x, v4.y, eang);
    *(ushort4*)(bins + i0) = make_ushort4((unsigned short)b0, (unsigned short)b1,
                                          (unsigned short)b2, (unsigned short)b3);
    if (b0 < HV) atomicAdd(&lh[b0], 1);
    if (b1 < HV) atomicAdd(&lh[b1], 1);
    if (b2 < HV) atomicAdd(&lh[b2], 1);
    if (b3 < HV) atomicAdd(&lh[b3], 1);
  }
  for (int i = endq + tid; i < end; i += BLK) {   // <=3 tail points
    size_t p = (size_t)i * 5;
    int b = point_bin(pts[p], pts[p + 1], pts[p + 2], eang);
    bins[i] = (unsigned short)b;
    if (b < HV) atomicAdd(&lh[b], 1);
  }
  __syncthreads();
  unsigned char* ht = hist + (size_t)t * HV;
  for (int i = tid; i < HV; i += BLK) ht[i] = (unsigned char)min(lh[i], 64);
}

// ---- pass 2a: per-chunk saturated sums (u32-packed u8 lanes) ----
__global__ void k_scan_a(const unsigned int* __restrict__ hist32, int NT,
                         unsigned int* __restrict__ part32) {
  int w = blockIdx.x * BLK + threadIdx.x;     // word 0..HVW-1 (4 bins per word)
  int c = blockIdx.y;
  if (w >= HVW) return;
  int t0 = c * CHT, t1 = min(t0 + CHT, NT);
  int s0 = 0, s1 = 0, s2 = 0, s3 = 0;
  for (int t = t0; t < t1; ++t) {
    unsigned int v = hist32[(size_t)t * HVW + w];
    s0 = min(s0 + (int)(v & 255u), 64);
    s1 = min(s1 + (int)((v >> 8) & 255u), 64);
    s2 = min(s2 + (int)((v >> 16) & 255u), 64);
    s3 = min(s3 + (int)(v >> 24), 64);
  }
  part32[(size_t)c * HVW + w] = (unsigned)s0 | ((unsigned)s1 << 8) |
                                ((unsigned)s2 << 16) | ((unsigned)s3 << 24);
}

// ---- pass 2b fused: chunk-exclusive scan + slot assignment + coords/num/centers ----
__global__ __launch_bounds__(1024) void k_bsc(unsigned int* __restrict__ part32, int NC,
                                              int* __restrict__ soh,
                                              float* __restrict__ out) {
  __shared__ float eang[73];
  __shared__ int ssum[1024];
  int tid = threadIdx.x;
  if (tid < 73) eang[tid] = angle_edge(tid);
  int r0 = 0, r1 = 0, r2 = 0, r3 = 0;
  for (int cb = 0; cb < NC; cb += 16) {
    unsigned int vv[16];
#pragma unroll
    for (int k = 0; k < 16; ++k) {
      int c = cb + k;
      vv[k] = (tid < HVW && c < NC) ? part32[(size_t)c * HVW + tid] : 0u;
    }
#pragma unroll
    for (int k = 0; k < 16; ++k) {
      int c = cb + k;
      if (tid < HVW && c < NC)
        part32[(size_t)c * HVW + tid] = (unsigned)r0 | ((unsigned)r1 << 8) |
                                        ((unsigned)r2 << 16) | ((unsigned)r3 << 24);
      r0 = min(r0 + (int)(vv[k] & 255u), 64);
      r1 = min(r1 + (int)((vv[k] >> 8) & 255u), 64);
      r2 = min(r2 + (int)((vv[k] >> 16) & 255u), 64);
      r3 = min(r3 + (int)(vv[k] >> 24), 64);
    }
  }
  int c0 = r0, c1 = r1, c2 = r2, c3 = r3;
  int occ = (c0 > 0) + (c1 > 0) + (c2 > 0) + (c3 > 0);
  if (tid >= HVW) occ = 0;
  ssum[tid] = occ;
  __syncthreads();
  for (int off = 1; off < 1024; off <<= 1) {
    int v = (tid >= off) ? ssum[tid - off] : 0;
    __syncthreads();
    ssum[tid] += v;
    __syncthreads();
  }
  int base = ssum[tid] - occ;                 // exclusive slot base (bin order)
  if (tid < HVW) {
    int cs[4] = {c0, c1, c2, c3};
#pragma unroll
    for (int k = 0; k < 4; ++k) {
      int h = tid * 4 + k;
      int cnt = cs[k];
      int s = -1;
      if (cnt > 0) {
        if (base < MAXV) s = base;
        base++;
      }
      soh[h] = s;
      if (s >= 0) {
        int ri = h / NANG, ti = h % NANG;
        out[OFF_C + s * 3 + 0] = (float)ri;
        out[OFF_C + s * 3 + 1] = (float)ti;
        out[OFF_C + s * 3 + 2] = 0.0f;
        out[OFF_N + s] = (float)cnt;          // already saturated at 64
        float rc = 2.5f + (float)ri;
        float tc = 0.5f * (eang[ti] + eang[ti + 1]);
        out[OFF_X + s * 2 + 0] = rc * cosf(tc);   // ~5e-5 abs err << threshold
        out[OFF_X + s * 2 + 1] = rc * sinf(tc);
      }
    }
  }
}

// ---- pass 2c: in-place exclusive tile-start scan within each chunk (saturated) ----
__global__ void k_scan_c(unsigned int* __restrict__ hist32, int NT,
                         const unsigned int* __restrict__ part32) {
  int w = blockIdx.x * BLK + threadIdx.x;
  int c = blockIdx.y;
  if (w >= HVW) return;
  int t0 = c * CHT, t1 = min(t0 + CHT, NT);
  unsigned int pv = part32[(size_t)c * HVW + w];
  int r0 = pv & 255u, r1 = (pv >> 8) & 255u, r2 = (pv >> 16) & 255u, r3 = pv >> 24;
  for (int t = t0; t < t1; ++t) {
    size_t o = (size_t)t * HVW + w;
    unsigned int v = hist32[o];
    hist32[o] = (unsigned)r0 | ((unsigned)r1 << 8) |
                ((unsigned)r2 << 16) | ((unsigned)r3 << 24);
    r0 = min(r0 + (int)(v & 255u), 64);
    r1 = min(r1 + (int)((v >> 8) & 255u), 64);
    r2 = min(r2 + (int)((v >> 16) & 255u), 64);
    r3 = min(r3 + (int)(v >> 24), 64);
  }
}

// ---- pass 3 (fast, tile==4096): ballot-rank scatter with dead-bin pruning ----
// ht[b]==64 (saturated tile start) => every point of bin b in this tile has
// rank>=64 and can never be written; prune those lanes before the match loop
// and skip whole chunks with no live lane. Pruned lanes are other bins, so
// live bins' cursor counts are unaffected.
__global__ __launch_bounds__(BLK) void k_scatter_fast(
    const float* __restrict__ pts, int N,
    const unsigned char* __restrict__ hist, const unsigned short* __restrict__ bins,
    const int* __restrict__ soh, float* __restrict__ out) {
  __shared__ unsigned int whd[4 * HV / 2];          // 4 x HV u16 = 27648 B
  unsigned short (*wh)[HV] = (unsigned short (*)[HV])whd;
  int t = blockIdx.x;
  int tid = threadIdx.x;
  int lane = tid & 63, wv = tid >> 6;
  for (int i = tid; i < 4 * HV / 2; i += BLK) whd[i] = 0u;
  __syncthreads();
  int base = t * TILE;
  int end  = min(base + TILE, N);
  int sb = base + wv * SUBT;
  int se = min(sb + SUBT, end);
  const unsigned char* ht = hist + (size_t)t * HV;  // saturated tile-start offsets
  unsigned short lb[NCH], lr[NCH];
  const unsigned long long lmask = (1ULL << lane) - 1ULL;
#pragma unroll
  for (int c = 0; c < NCH; ++c) {
    int i = sb + c * 64 + lane;
    int b = 4095;                                   // sentinel (> any real bin)
    if (i < se) {
      int bi = bins[i];
      if (bi < HV && ht[bi] < 64) b = bi;           // prune dead bins
    }
    lb[c] = (unsigned short)b;
    lr[c] = 0;
    if (__ballot(b != 4095) == 0ULL) continue;      // whole chunk dead
    unsigned long long m = ~0ULL;
#pragma unroll
    for (int k = 0; k < 12; ++k) {
      unsigned long long bal = __ballot((b >> k) & 1);
      m &= ((b >> k) & 1) ? bal : ~bal;
    }
    int rho = __popcll(m & lmask);                  // same-bin lanes before me
    int kap = __popcll(m);                          // same-bin lanes in chunk
    int cv = 0;
    if (b != 4095) {
      cv = wh[wv][b];                               // read before leader write
      if (rho == 0) wh[wv][b] = (unsigned short)(cv + kap);
    }
    lr[c] = (unsigned short)(cv + rho);
  }
  __syncthreads();
  for (int j = tid; j < HV; j += BLK) {
    int a0 = wh[0][j], a1 = wh[1][j], a2 = wh[2][j];
    wh[0][j] = 0;
    wh[1][j] = (unsigned short)a0;
    wh[2][j] = (unsigned short)(a0 + a1);
    wh[3][j] = (unsigned short)(a0 + a1 + a2);
  }
  __syncthreads();
#pragma unroll
  for (int c = 0; c < NCH; ++c) {
    int b = lb[c];
    if (b == 4095) continue;
    int rank = (int)ht[b] + (int)wh[wv][b] + (int)lr[c];
    if (rank < MAXP) {
      int s = soh[b];
      if (s >= 0) {
        int i = sb + c * 64 + lane;
        size_t dst = (size_t)(s * MAXP + rank) * 5;
        size_t src = (size_t)i * 5;
        out[dst + 0] = pts[src + 0];
        out[dst + 1] = pts[src + 1];
        out[dst + 2] = pts[src + 2];
        out[dst + 3] = pts[src + 3];
        out[dst + 4] = pts[src + 4];
      }
    }
  }
}

// ---- pass 3 (generic fallback, any tile) ----
__global__ void k_scatter_gen(const float* __restrict__ pts, int N, int tile,
                              const unsigned char* __restrict__ hist,
                              const unsigned short* __restrict__ bins,
                              const int* __restrict__ soh,
                              float* __restrict__ out) {
  __shared__ int cur[HV + 1];
  int t = blockIdx.x;
  int tid = threadIdx.x;
  const unsigned char* ht = hist + (size_t)t * HV;
  for (int i = tid; i < HV + 1; i += BLK) cur[i] = (i < HV) ? (int)ht[i] : 0;
  __syncthreads();
  int base = t * tile;
  int end  = min(base + tile, N);
  int lane = tid & 63, wv = tid >> 6;
  for (int g = base; g < base + tile; g += BLK) {
    int i = g + tid;
    bool act = (i < end);
    int b = act ? (int)bins[i] : 0x10000;
    int rho = 0, kap = 0;
    for (int j = 0; j < 64; ++j) {
      int bj = __shfl(b, j, 64);
      if (bj == b) { kap++; if (j < lane) rho++; }
    }
    int rank = 0x7FFFFFFF;
    for (int w = 0; w < 4; ++w) {
      if (wv == w && act) {
        int bs = cur[b];
        rank = bs + rho;
        if (rho == 0) cur[b] = bs + kap;
      }
      __syncthreads();
    }
    if (act && rank < MAXP && b < HV) {
      int s = soh[b];
      if (s >= 0) {
        size_t dst = (size_t)(s * MAXP + rank) * 5;
        size_t src = (size_t)i * 5;
        out[dst + 0] = pts[src + 0];
        out[dst + 1] = pts[src + 1];
        out[dst + 2] = pts[src + 2];
        out[dst + 3] = pts[src + 3];
        out[dst + 4] = pts[src + 4];
      }
    }
  }
}

extern "C" void kernel_launch(void* const* d_in, const int* in_sizes, int n_in,
                              void* d_out, int out_size, void* d_ws, size_t ws_size,
                              hipStream_t stream) {
  const float* pts = (const float*)d_in[0];
  int N = in_sizes[0] / 5;
  float* out = (float*)d_out;

  auto align = [](size_t x) { return (x + 255) & ~(size_t)255; };
  int tile = TILE, NT = 1, NC = 1;
  size_t o_hist = 0, o_part = 0, o_soh = 0, o_bins = 0;
  for (;;) {
    NT = (N + tile - 1) / tile;
    NC = (NT + CHT - 1) / CHT;
    o_hist = 0;
    o_part = align(o_hist + (size_t)NT * HV);
    o_soh  = align(o_part + (size_t)NC * HV);
    o_bins = align(o_soh + (size_t)HV * 4);
    size_t need = o_bins + (size_t)N * 2;
    if (need <= ws_size || tile >= (1 << 22)) break;
    tile <<= 1;
  }

  char* w = (char*)d_ws;
  unsigned char* hist = (unsigned char*)(w + o_hist);
  unsigned int*  hist32 = (unsigned int*)hist;
  unsigned int*  part32 = (unsigned int*)(w + o_part);
  int* soh = (int*)(w + o_soh);
  unsigned short* bins = (unsigned short*)(w + o_bins);

  int n4 = out_size / 4;
  int tailN = out_size - n4 * 4;

  k_hist<<<NT, BLK, 0, stream>>>(pts, N, tile, n4, tailN, hist, bins, (float4*)out);
  dim3 ga((HVW + BLK - 1) / BLK, NC);
  k_scan_a<<<ga, BLK, 0, stream>>>(hist32, NT, part32);
  k_bsc<<<1, 1024, 0, stream>>>(part32, NC, soh, out);
  k_scan_c<<<ga, BLK, 0, stream>>>(hist32, NT, part32);
  if (tile == TILE) {
    k_scatter_fast<<<NT, BLK, 0, stream>>>(pts, N, hist, bins, soh, out);
  } else {
    k_scatter_gen<<<NT, BLK, 0, stream>>>(pts, N, tile, hist, bins, soh, out);
  }
}